// Round 1
// baseline (4281.771 us; speedup 1.0000x reference)
//
#include <hip/hip_runtime.h>
#include <math.h>

#define NLAYERS 4
#define H 4
#define C 64
#define D 64
#define HC 256     // H*C
#define D3 192     // 3*D
#define NEG 0.2f

// ---- monotone float<->uint encoding for atomicMax-based segment max ----
__device__ __forceinline__ unsigned fenc(float f) {
    unsigned u = __float_as_uint(f);
    return (u & 0x80000000u) ? ~u : (u | 0x80000000u);
}
__device__ __forceinline__ float fdec(unsigned u) {
    return (u & 0x80000000u) ? __uint_as_float(u & 0x7FFFFFFFu) : __uint_as_float(~u);
}

// ---- K0: w_eff[d,h] = sum_c W_edge[d, h*C+c] * att_edge[h,c]  (one block, 256 thr) ----
__global__ void k_weff(const float* __restrict__ W_edge, const float* __restrict__ att_edge,
                       float* __restrict__ weff) {
    int t = threadIdx.x;            // 0..255
    int d = t >> 2, h = t & 3;
    float s = 0.f;
    #pragma unroll
    for (int c = 0; c < C; ++c)
        s = fmaf(W_edge[d * HC + h * C + c], att_edge[h * C + c], s);
    weff[d * H + h] = s;            // layout [d][h]
}

// ---- K1: x = nf @ W_lin  [N,256]; a_src[n,h], a_dst[n,h] via wave reductions ----
__global__ void k_nodeproj(const float* __restrict__ nf, const float* __restrict__ W,
                           const float* __restrict__ att_s, const float* __restrict__ att_d,
                           float* __restrict__ x, float* __restrict__ a_src,
                           float* __restrict__ a_dst, int N, int relu_in) {
    int n = blockIdx.x;
    int t = threadIdx.x;            // 0..255 -> output channel
    __shared__ float s_nf[D];
    if (t < D) {
        float v = nf[(size_t)n * D + t];
        if (relu_in) v = fmaxf(v, 0.f);
        s_nf[t] = v;
    }
    __syncthreads();
    float acc = 0.f;
    #pragma unroll
    for (int d = 0; d < D; ++d)
        acc = fmaf(s_nf[d], W[d * HC + t], acc);
    x[(size_t)n * HC + t] = acc;
    int h = t >> 6, c = t & 63;     // wave h, lane c
    float ps = acc * att_s[h * C + c];
    float pd = acc * att_d[h * C + c];
    #pragma unroll
    for (int off = 32; off; off >>= 1) {
        ps += __shfl_xor(ps, off);
        pd += __shfl_xor(pd, off);
    }
    if (c == 0) { a_src[n * H + h] = ps; a_dst[n * H + h] = pd; }
}

// ---- K2: per-edge alpha (leaky-relu'd) + segment max over dst.  One wave per edge. ----
__global__ void k_alpha(const float* __restrict__ ef, const float* __restrict__ weff,
                        const int* __restrict__ src, const int* __restrict__ dst,
                        const float* __restrict__ a_src, const float* __restrict__ a_dst,
                        float* __restrict__ alpha, unsigned* __restrict__ amax, int E) {
    int wave = (int)((blockIdx.x * blockDim.x + threadIdx.x) >> 6);
    int lane = threadIdx.x & 63;
    if (wave >= E) return;
    float efc = ef[(size_t)wave * D + lane];
    float p0 = efc * weff[lane * H + 0];
    float p1 = efc * weff[lane * H + 1];
    float p2 = efc * weff[lane * H + 2];
    float p3 = efc * weff[lane * H + 3];
    #pragma unroll
    for (int off = 32; off; off >>= 1) {
        p0 += __shfl_xor(p0, off);
        p1 += __shfl_xor(p1, off);
        p2 += __shfl_xor(p2, off);
        p3 += __shfl_xor(p3, off);
    }
    if (lane < 4) {
        float p = (lane == 0) ? p0 : (lane == 1) ? p1 : (lane == 2) ? p2 : p3;
        int s = src[wave], dd = dst[wave];
        float a = p + a_src[s * H + lane] + a_dst[dd * H + lane];
        a = (a > 0.f) ? a : NEG * a;
        alpha[(size_t)wave * H + lane] = a;
        atomicMax(&amax[dd * H + lane], fenc(a));
    }
}

// ---- K3: alpha = exp(alpha - amax[dst]); denom += alpha ----
__global__ void k_expdenom(float* __restrict__ alpha, const unsigned* __restrict__ amax,
                           const int* __restrict__ dst, float* __restrict__ denom, int EH) {
    int i = blockIdx.x * blockDim.x + threadIdx.x;
    if (i >= EH) return;
    int e = i >> 2, h = i & 3;
    int dd = dst[e];
    float a = expf(alpha[i] - fdec(amax[dd * H + h]));
    alpha[i] = a;
    atomicAdd(&denom[dd * H + h], a);
}

// ---- K4: acc[dst,c] += sum_h (alpha/denom) * x[src, h*64+c] / H.  One wave per edge. ----
__global__ void k_aggregate(const float* __restrict__ x, const float* __restrict__ alpha,
                            const float* __restrict__ denom, const int* __restrict__ src,
                            const int* __restrict__ dst, float* __restrict__ acc, int E) {
    int wave = (int)((blockIdx.x * blockDim.x + threadIdx.x) >> 6);
    int lane = threadIdx.x & 63;
    if (wave >= E) return;
    int s = src[wave], dd = dst[wave];
    float w0 = alpha[(size_t)wave * 4 + 0] / (denom[dd * 4 + 0] + 1e-16f) * 0.25f;
    float w1 = alpha[(size_t)wave * 4 + 1] / (denom[dd * 4 + 1] + 1e-16f) * 0.25f;
    float w2 = alpha[(size_t)wave * 4 + 2] / (denom[dd * 4 + 2] + 1e-16f) * 0.25f;
    float w3 = alpha[(size_t)wave * 4 + 3] / (denom[dd * 4 + 3] + 1e-16f) * 0.25f;
    const float* xr = x + (size_t)s * HC;
    float contrib = w0 * xr[lane] + w1 * xr[64 + lane] + w2 * xr[128 + lane] + w3 * xr[192 + lane];
    atomicAdd(&acc[(size_t)dd * D + lane], contrib);
}

// ---- K5: node out = LN(acc + bias).  One wave per node. ----
__global__ void k_nodeln(const float* __restrict__ acc, const float* __restrict__ bias,
                         const float* __restrict__ g, const float* __restrict__ b,
                         float* __restrict__ nf_ln, float* __restrict__ out2, int N) {
    int n = (int)((blockIdx.x * blockDim.x + threadIdx.x) >> 6);
    int lane = threadIdx.x & 63;
    if (n >= N) return;
    float v = acc[(size_t)n * D + lane] + bias[lane];
    float s = v;
    #pragma unroll
    for (int off = 32; off; off >>= 1) s += __shfl_xor(s, off);
    float mu = s * (1.f / 64.f);
    float dv = v - mu;
    float q = dv * dv;
    #pragma unroll
    for (int off = 32; off; off >>= 1) q += __shfl_xor(q, off);
    float rstd = rsqrtf(q * (1.f / 64.f) + 1e-5f);
    float r = dv * rstd * g[lane] + b[lane];
    nf_ln[(size_t)n * D + lane] = r;
    if (out2) out2[(size_t)n * D + lane] = r;
}

// ---- K6: fused edge MLP.  192 threads, 32 edges per block. In-place safe on ef. ----
__global__ __launch_bounds__(192) void k_edgemlp(
    const float* __restrict__ nf, const float* __restrict__ ef_in,
    const int* __restrict__ src, const int* __restrict__ dst,
    const float* __restrict__ W1, const float* __restrict__ b1,
    const float* __restrict__ lg, const float* __restrict__ lb,
    const float* __restrict__ W2, const float* __restrict__ b2,
    float* __restrict__ ef_out, int E) {
    __shared__ __align__(16) float hT[D3 * 36];   // h_in transposed [k][e], pad 36 for f4 align
    __shared__ __align__(16) float h1[32 * 196];  // h1 [e][c], pad 196 (%4==0, %32==4)
    __shared__ float mu_s[32], rstd_s[32];
    int t = threadIdx.x;            // 0..191
    int e0 = blockIdx.x * 32;

    // phase 1: build h_in = [ni+nj | |ni-nj| | ef] into hT[k][e]
    for (int e = 0; e < 32; ++e) {
        int ge = e0 + e;
        float v = 0.f;
        if (ge < E) {
            int s = src[ge], dd = dst[ge];
            if (t < 64)        v = nf[(size_t)s * D + t] + nf[(size_t)dd * D + t];
            else if (t < 128)  v = fabsf(nf[(size_t)s * D + (t - 64)] - nf[(size_t)dd * D + (t - 64)]);
            else               v = ef_in[(size_t)ge * D + (t - 128)];
        }
        hT[t * 36 + e] = v;
    }
    __syncthreads();

    // GEMM1: thread t owns output column c = t of h1_pre = h_in @ W1 + b1
    float accv[32];
    {
        float bb = b1[t];
        #pragma unroll
        for (int e = 0; e < 32; ++e) accv[e] = bb;
    }
    for (int k = 0; k < D3; ++k) {
        float w = W1[k * D3 + t];                       // coalesced, L2-resident
        const float4* hp = (const float4*)&hT[k * 36];  // wave-uniform broadcast reads
        #pragma unroll
        for (int e4 = 0; e4 < 8; ++e4) {
            float4 h4 = hp[e4];
            accv[e4 * 4 + 0] = fmaf(h4.x, w, accv[e4 * 4 + 0]);
            accv[e4 * 4 + 1] = fmaf(h4.y, w, accv[e4 * 4 + 1]);
            accv[e4 * 4 + 2] = fmaf(h4.z, w, accv[e4 * 4 + 2]);
            accv[e4 * 4 + 3] = fmaf(h4.w, w, accv[e4 * 4 + 3]);
        }
    }
    #pragma unroll
    for (int e = 0; e < 32; ++e) h1[e * 196 + t] = accv[e];
    __syncthreads();

    // LN stats per edge (threads 0..31)
    if (t < 32) {
        float s1 = 0.f;
        for (int k = 0; k < D3; ++k) s1 += h1[t * 196 + k];
        float mu = s1 * (1.f / 192.f);
        float s2 = 0.f;
        for (int k = 0; k < D3; ++k) { float d2 = h1[t * 196 + k] - mu; s2 += d2 * d2; }
        mu_s[t] = mu;
        rstd_s[t] = rsqrtf(s2 * (1.f / 192.f) + 1e-5f);
    }
    __syncthreads();

    // apply LN + relu in place (thread t = channel)
    {
        float gg = lg[t], bb = lb[t];
        #pragma unroll
        for (int e = 0; e < 32; ++e) {
            float v = (h1[e * 196 + t] - mu_s[e]) * rstd_s[e] * gg + bb;
            h1[e * 196 + t] = fmaxf(v, 0.f);
        }
    }
    __syncthreads();

    // GEMM2 + residual: wave eh handles edges {eh, eh+3, ...}; lane c2 = out channel
    int c2 = t & 63, eh = t >> 6;
    float acc2[11];
    #pragma unroll
    for (int j = 0; j < 11; ++j) acc2[j] = 0.f;
    for (int k4 = 0; k4 < D3; k4 += 4) {
        float w0 = W2[(k4 + 0) * D + c2];
        float w1 = W2[(k4 + 1) * D + c2];
        float w2 = W2[(k4 + 2) * D + c2];
        float w3 = W2[(k4 + 3) * D + c2];
        #pragma unroll
        for (int j = 0; j < 11; ++j) {
            int e = eh + 3 * j;
            if (e < 32) {
                float4 h4 = *(const float4*)&h1[e * 196 + k4];  // aligned, broadcast
                acc2[j] = fmaf(h4.x, w0, fmaf(h4.y, w1, fmaf(h4.z, w2, fmaf(h4.w, w3, acc2[j]))));
            }
        }
    }
    float bb2 = b2[c2];
    #pragma unroll
    for (int j = 0; j < 11; ++j) {
        int e = eh + 3 * j;
        if (e < 32) {
            int ge = e0 + e;
            if (ge < E)
                ef_out[(size_t)ge * D + c2] = acc2[j] + bb2 + ef_in[(size_t)ge * D + c2];
        }
    }
}

extern "C" void kernel_launch(void* const* d_in, const int* in_sizes, int n_in,
                              void* d_out, int out_size, void* d_ws, size_t ws_size,
                              hipStream_t stream) {
    const float* nf_in0   = (const float*)d_in[0];
    const float* ef_in0   = (const float*)d_in[1];
    const int*   eidx     = (const int*)d_in[2];
    const float* W_lin    = (const float*)d_in[3];
    const float* W_edge   = (const float*)d_in[4];
    const float* att_src  = (const float*)d_in[5];
    const float* att_dst  = (const float*)d_in[6];
    const float* att_edge = (const float*)d_in[7];
    const float* biasc    = (const float*)d_in[8];
    const float* ln_g     = (const float*)d_in[9];
    const float* ln_b     = (const float*)d_in[10];
    const float* eW1      = (const float*)d_in[11];
    const float* eb1      = (const float*)d_in[12];
    const float* eln_g    = (const float*)d_in[13];
    const float* eln_b    = (const float*)d_in[14];
    const float* eW2      = (const float*)d_in[15];
    const float* eb2      = (const float*)d_in[16];

    int N = in_sizes[0] / D;
    int E = in_sizes[1] / D;
    const int* srcp = eidx;
    const int* dstp = eidx + E;

    float* ws      = (float*)d_ws;
    float* x       = ws;                              // N*256
    float* a_src   = x + (size_t)N * HC;              // N*4
    float* a_dst   = a_src + (size_t)N * H;           // N*4
    unsigned* amax = (unsigned*)(a_dst + (size_t)N * H); // N*4
    float* denom   = (float*)(amax + (size_t)N * H);  // N*4
    float* alpha   = denom + (size_t)N * H;           // E*4
    float* acc     = alpha + (size_t)E * H;           // N*64
    float* nf_ln   = acc + (size_t)N * D;             // N*64
    float* weff    = nf_ln + (size_t)N * D;           // 256

    float* out_nf = (float*)d_out;
    float* out_ef = out_nf + (size_t)N * D;

    for (int l = 0; l < NLAYERS; ++l) {
        const float* nf_cur = (l == 0) ? nf_in0 : nf_ln;
        const float* ef_cur = (l == 0) ? ef_in0 : out_ef;
        int relu_in = (l > 0) ? 1 : 0;

        // zero segment-max (enc(-inf)=0), denom, and node accumulator
        hipMemsetAsync(amax, 0, (size_t)N * H * 2 * sizeof(float), stream);
        hipMemsetAsync(acc, 0, (size_t)N * D * sizeof(float), stream);

        k_weff<<<1, 256, 0, stream>>>(W_edge + (size_t)l * D * HC, att_edge + l * H * C, weff);
        k_nodeproj<<<N, 256, 0, stream>>>(nf_cur, W_lin + (size_t)l * D * HC,
                                          att_src + l * H * C, att_dst + l * H * C,
                                          x, a_src, a_dst, N, relu_in);
        k_alpha<<<(E + 3) / 4, 256, 0, stream>>>(ef_cur, weff, srcp, dstp, a_src, a_dst,
                                                 alpha, amax, E);
        k_expdenom<<<(E * H + 255) / 256, 256, 0, stream>>>(alpha, amax, dstp, denom, E * H);
        k_aggregate<<<(E + 3) / 4, 256, 0, stream>>>(x, alpha, denom, srcp, dstp, acc, E);
        k_nodeln<<<(N + 3) / 4, 256, 0, stream>>>(acc, biasc + l * D, ln_g + l * D, ln_b + l * D,
                                                  nf_ln, (l == NLAYERS - 1) ? out_nf : nullptr, N);
        k_edgemlp<<<(E + 31) / 32, 192, 0, stream>>>(nf_ln, ef_cur, srcp, dstp,
                                                     eW1 + (size_t)l * D3 * D3, eb1 + l * D3,
                                                     eln_g + l * D3, eln_b + l * D3,
                                                     eW2 + (size_t)l * D3 * D, eb2 + l * D,
                                                     out_ef, E);
    }
}

// Round 2
// 2002.432 us; speedup vs baseline: 2.1383x; 2.1383x over previous
//
#include <hip/hip_runtime.h>
#include <math.h>

#define NLAYERS 4
#define H 4
#define C 64
#define D 64
#define HC 256     // H*C
#define D3 192     // 3*D
#define NEG 0.2f

typedef float f32x4 __attribute__((ext_vector_type(4)));
typedef short bf16x8 __attribute__((ext_vector_type(8)));
typedef unsigned short u16;

// ---- monotone float<->uint encoding for atomicMax-based segment max ----
__device__ __forceinline__ unsigned fenc(float f) {
    unsigned u = __float_as_uint(f);
    return (u & 0x80000000u) ? ~u : (u | 0x80000000u);
}
__device__ __forceinline__ float fdec(unsigned u) {
    return (u & 0x80000000u) ? __uint_as_float(u & 0x7FFFFFFFu) : __uint_as_float(~u);
}

// fp32 -> bf16 round-to-nearest-even
__device__ __forceinline__ u16 f2bf(float f) {
    unsigned u = __float_as_uint(f);
    u += 0x7FFFu + ((u >> 16) & 1u);
    return (u16)(u >> 16);
}

// ---- K0: w_eff[d,h] = sum_c W_edge[d, h*C+c] * att_edge[h,c]  (one block, 256 thr) ----
__global__ void k_weff(const float* __restrict__ W_edge, const float* __restrict__ att_edge,
                       float* __restrict__ weff) {
    int t = threadIdx.x;            // 0..255
    int d = t >> 2, h = t & 3;
    float s = 0.f;
    #pragma unroll
    for (int c = 0; c < C; ++c)
        s = fmaf(W_edge[d * HC + h * C + c], att_edge[h * C + c], s);
    weff[d * H + h] = s;            // layout [d][h]
}

// ---- K0b: convert W1 -> W1^T bf16 [l][n][k], W2 -> W2^T bf16 [l][n][k] ----
__global__ void k_cvtw(const float* __restrict__ W1, const float* __restrict__ W2,
                       u16* __restrict__ W1T, u16* __restrict__ W2T) {
    int i = blockIdx.x * 256 + threadIdx.x;
    if (i < NLAYERS * D3 * D3) {
        int l = i / (D3 * D3), r = i % (D3 * D3);
        int n = r / D3, k = r % D3;
        W1T[i] = f2bf(W1[l * D3 * D3 + k * D3 + n]);
    } else {
        int j = i - NLAYERS * D3 * D3;
        if (j < NLAYERS * D3 * D) {
            int l = j / (D3 * D), r = j % (D3 * D);
            int n = r / D3, k = r % D3;
            W2T[j] = f2bf(W2[l * D3 * D + k * D + n]);
        }
    }
}

// ---- K1: x = nf @ W_lin  [N,256]; a_src[n,h], a_dst[n,h] via wave reductions ----
__global__ void k_nodeproj(const float* __restrict__ nf, const float* __restrict__ W,
                           const float* __restrict__ att_s, const float* __restrict__ att_d,
                           float* __restrict__ x, float* __restrict__ a_src,
                           float* __restrict__ a_dst, int N, int relu_in) {
    int n = blockIdx.x;
    int t = threadIdx.x;            // 0..255 -> output channel
    __shared__ float s_nf[D];
    if (t < D) {
        float v = nf[(size_t)n * D + t];
        if (relu_in) v = fmaxf(v, 0.f);
        s_nf[t] = v;
    }
    __syncthreads();
    float acc = 0.f;
    #pragma unroll
    for (int d = 0; d < D; ++d)
        acc = fmaf(s_nf[d], W[d * HC + t], acc);
    x[(size_t)n * HC + t] = acc;
    int h = t >> 6, c = t & 63;     // wave h, lane c
    float ps = acc * att_s[h * C + c];
    float pd = acc * att_d[h * C + c];
    #pragma unroll
    for (int off = 32; off; off >>= 1) {
        ps += __shfl_xor(ps, off);
        pd += __shfl_xor(pd, off);
    }
    if (c == 0) { a_src[n * H + h] = ps; a_dst[n * H + h] = pd; }
}

// ---- K2: per-edge alpha (leaky-relu'd) + segment max over dst.  One wave per edge. ----
__global__ void k_alpha(const float* __restrict__ ef, const float* __restrict__ weff,
                        const int* __restrict__ src, const int* __restrict__ dst,
                        const float* __restrict__ a_src, const float* __restrict__ a_dst,
                        float* __restrict__ alpha, unsigned* __restrict__ amax, int E) {
    int wave = (int)((blockIdx.x * blockDim.x + threadIdx.x) >> 6);
    int lane = threadIdx.x & 63;
    if (wave >= E) return;
    float efc = ef[(size_t)wave * D + lane];
    float p0 = efc * weff[lane * H + 0];
    float p1 = efc * weff[lane * H + 1];
    float p2 = efc * weff[lane * H + 2];
    float p3 = efc * weff[lane * H + 3];
    #pragma unroll
    for (int off = 32; off; off >>= 1) {
        p0 += __shfl_xor(p0, off);
        p1 += __shfl_xor(p1, off);
        p2 += __shfl_xor(p2, off);
        p3 += __shfl_xor(p3, off);
    }
    if (lane < 4) {
        float p = (lane == 0) ? p0 : (lane == 1) ? p1 : (lane == 2) ? p2 : p3;
        int s = src[wave], dd = dst[wave];
        float a = p + a_src[s * H + lane] + a_dst[dd * H + lane];
        a = (a > 0.f) ? a : NEG * a;
        alpha[(size_t)wave * H + lane] = a;
        atomicMax(&amax[dd * H + lane], fenc(a));
    }
}

// ---- K3: alpha = exp(alpha - amax[dst]); denom += alpha ----
__global__ void k_expdenom(float* __restrict__ alpha, const unsigned* __restrict__ amax,
                           const int* __restrict__ dst, float* __restrict__ denom, int EH) {
    int i = blockIdx.x * blockDim.x + threadIdx.x;
    if (i >= EH) return;
    int e = i >> 2, h = i & 3;
    int dd = dst[e];
    float a = expf(alpha[i] - fdec(amax[dd * H + h]));
    alpha[i] = a;
    atomicAdd(&denom[dd * H + h], a);
}

// ---- K4: acc[dst,c] += sum_h (alpha/denom) * x[src, h*64+c] / H.  One wave per edge. ----
__global__ void k_aggregate(const float* __restrict__ x, const float* __restrict__ alpha,
                            const float* __restrict__ denom, const int* __restrict__ src,
                            const int* __restrict__ dst, float* __restrict__ acc, int E) {
    int wave = (int)((blockIdx.x * blockDim.x + threadIdx.x) >> 6);
    int lane = threadIdx.x & 63;
    if (wave >= E) return;
    int s = src[wave], dd = dst[wave];
    float w0 = alpha[(size_t)wave * 4 + 0] / (denom[dd * 4 + 0] + 1e-16f) * 0.25f;
    float w1 = alpha[(size_t)wave * 4 + 1] / (denom[dd * 4 + 1] + 1e-16f) * 0.25f;
    float w2 = alpha[(size_t)wave * 4 + 2] / (denom[dd * 4 + 2] + 1e-16f) * 0.25f;
    float w3 = alpha[(size_t)wave * 4 + 3] / (denom[dd * 4 + 3] + 1e-16f) * 0.25f;
    const float* xr = x + (size_t)s * HC;
    float contrib = w0 * xr[lane] + w1 * xr[64 + lane] + w2 * xr[128 + lane] + w3 * xr[192 + lane];
    atomicAdd(&acc[(size_t)dd * D + lane], contrib);
}

// ---- K5: node out = LN(acc + bias).  One wave per node. ----
__global__ void k_nodeln(const float* __restrict__ acc, const float* __restrict__ bias,
                         const float* __restrict__ g, const float* __restrict__ b,
                         float* __restrict__ nf_ln, float* __restrict__ out2, int N) {
    int n = (int)((blockIdx.x * blockDim.x + threadIdx.x) >> 6);
    int lane = threadIdx.x & 63;
    if (n >= N) return;
    float v = acc[(size_t)n * D + lane] + bias[lane];
    float s = v;
    #pragma unroll
    for (int off = 32; off; off >>= 1) s += __shfl_xor(s, off);
    float mu = s * (1.f / 64.f);
    float dv = v - mu;
    float q = dv * dv;
    #pragma unroll
    for (int off = 32; off; off >>= 1) q += __shfl_xor(q, off);
    float rstd = rsqrtf(q * (1.f / 64.f) + 1e-5f);
    float r = dv * rstd * g[lane] + b[lane];
    nf_ln[(size_t)n * D + lane] = r;
    if (out2) out2[(size_t)n * D + lane] = r;
}

// ---- K6: fused edge MLP with bf16 MFMA. 256 threads (4 waves), 32 edges/block. ----
// GEMM1: [32,192]@[192,192] via 16x16x32 bf16 MFMA, acc fp32, bias in acc-init.
// h1 staged fp32 in LDS -> wave-parallel LN stats -> LN+relu -> bf16 A2 (aliases A1)
// GEMM2: [32,192]@[192,64] + residual. In-place safe on ef (block-private rows).
__global__ __launch_bounds__(256, 4) void k_edgemlp_mfma(
    const float* __restrict__ nf, const float* __restrict__ ef_in,
    const int* __restrict__ src, const int* __restrict__ dst,
    const u16* __restrict__ W1T, const float* __restrict__ b1,
    const float* __restrict__ lg, const float* __restrict__ lb,
    const u16* __restrict__ W2T, const float* __restrict__ b2,
    float* __restrict__ ef_out, int E) {
    __shared__ __align__(16) u16 A1[32 * 200];      // bf16 A tile, pad 200 (also A2 alias)
    __shared__ __align__(16) float h1[32 * 196];    // fp32 GEMM1 out, pad 196
    __shared__ float mu_s[32], rstd_s[32];
    int tid = threadIdx.x;
    int w = tid >> 6, lane = tid & 63;
    int e0 = blockIdx.x * 32;

    // ---- phase 1: build h_in = [ni+nj | |ni-nj| | ef] as bf16 into A1[e][k] ----
    #pragma unroll
    for (int it = 0; it < 8; ++it) {
        int e = it * 4 + w;
        int ge = e0 + e;
        float a = 0.f, b = 0.f, f = 0.f;
        if (ge < E) {
            int s = src[ge], dd = dst[ge];
            a = nf[(size_t)s * D + lane];
            b = nf[(size_t)dd * D + lane];
            f = ef_in[(size_t)ge * D + lane];
        }
        A1[e * 200 + lane]       = f2bf(a + b);
        A1[e * 200 + 64 + lane]  = f2bf(fabsf(a - b));
        A1[e * 200 + 128 + lane] = f2bf(f);
    }
    __syncthreads();

    // ---- GEMM1: wave w owns output cols [w*48, w*48+48): 2 m-tiles x 3 n-tiles ----
    int m16 = lane & 15, kq = (lane >> 4) * 8;
    f32x4 acc[2][3];
    {
        #pragma unroll
        for (int nt = 0; nt < 3; ++nt) {
            float bv = b1[w * 48 + nt * 16 + m16];
            #pragma unroll
            for (int mt = 0; mt < 2; ++mt) {
                acc[mt][nt][0] = bv; acc[mt][nt][1] = bv;
                acc[mt][nt][2] = bv; acc[mt][nt][3] = bv;
            }
        }
    }
    #pragma unroll
    for (int ks = 0; ks < 6; ++ks) {
        int ko = ks * 32 + kq;
        bf16x8 af[2], bfr[3];
        af[0] = *(const bf16x8*)&A1[m16 * 200 + ko];
        af[1] = *(const bf16x8*)&A1[(16 + m16) * 200 + ko];
        #pragma unroll
        for (int nt = 0; nt < 3; ++nt) {
            int col = w * 48 + nt * 16 + m16;
            bfr[nt] = *(const bf16x8*)&W1T[col * D3 + ko];
        }
        #pragma unroll
        for (int mt = 0; mt < 2; ++mt)
            #pragma unroll
            for (int nt = 0; nt < 3; ++nt)
                acc[mt][nt] = __builtin_amdgcn_mfma_f32_16x16x32_bf16(af[mt], bfr[nt], acc[mt][nt], 0, 0, 0);
    }
    // store fp32 to h1: C layout col=lane&15, row=(lane>>4)*4+reg
    #pragma unroll
    for (int mt = 0; mt < 2; ++mt) {
        int row0 = mt * 16 + (lane >> 4) * 4;
        #pragma unroll
        for (int nt = 0; nt < 3; ++nt) {
            int col = w * 48 + nt * 16 + m16;
            #pragma unroll
            for (int r = 0; r < 4; ++r)
                h1[(row0 + r) * 196 + col] = acc[mt][nt][r];
        }
    }
    __syncthreads();

    // ---- LN stats: wave w handles edges w*8..w*8+7, lane-parallel ----
    for (int i = 0; i < 8; ++i) {
        int e = w * 8 + i;
        float v0 = h1[e * 196 + lane];
        float v1 = h1[e * 196 + 64 + lane];
        float v2 = h1[e * 196 + 128 + lane];
        float s = v0 + v1 + v2;
        float q = v0 * v0 + v1 * v1 + v2 * v2;
        #pragma unroll
        for (int off = 32; off; off >>= 1) {
            s += __shfl_xor(s, off);
            q += __shfl_xor(q, off);
        }
        if (lane == 0) {
            float mu = s * (1.f / 192.f);
            mu_s[e] = mu;
            rstd_s[e] = rsqrtf(q * (1.f / 192.f) - mu * mu + 1e-5f);
        }
    }
    __syncthreads();

    // ---- apply LN + relu, repack bf16 into A2 (aliases A1) ----
    unsigned* A2u = (unsigned*)A1;
    #pragma unroll
    for (int i = tid; i < 32 * 96; i += 256) {
        int e = i / 96, p = i % 96;
        int c0 = 2 * p;
        float mu = mu_s[e], rs = rstd_s[e];
        float v0 = fmaxf((h1[e * 196 + c0] - mu) * rs * lg[c0] + lb[c0], 0.f);
        float v1 = fmaxf((h1[e * 196 + c0 + 1] - mu) * rs * lg[c0 + 1] + lb[c0 + 1], 0.f);
        A2u[e * 100 + p] = (unsigned)f2bf(v0) | ((unsigned)f2bf(v1) << 16);
    }
    __syncthreads();

    // ---- GEMM2: wave w owns n-tile w (cols w*16..w*16+15), 2 m-tiles ----
    int col2 = w * 16 + m16;
    f32x4 acc2[2];
    {
        float bv = b2[col2];
        #pragma unroll
        for (int mt = 0; mt < 2; ++mt) {
            acc2[mt][0] = bv; acc2[mt][1] = bv; acc2[mt][2] = bv; acc2[mt][3] = bv;
        }
    }
    #pragma unroll
    for (int ks = 0; ks < 6; ++ks) {
        int ko = ks * 32 + kq;
        bf16x8 b2f = *(const bf16x8*)&W2T[col2 * D3 + ko];
        bf16x8 a2f0 = *(const bf16x8*)&A1[m16 * 200 + ko];
        bf16x8 a2f1 = *(const bf16x8*)&A1[(16 + m16) * 200 + ko];
        acc2[0] = __builtin_amdgcn_mfma_f32_16x16x32_bf16(a2f0, b2f, acc2[0], 0, 0, 0);
        acc2[1] = __builtin_amdgcn_mfma_f32_16x16x32_bf16(a2f1, b2f, acc2[1], 0, 0, 0);
    }
    // ---- store + residual ----
    #pragma unroll
    for (int mt = 0; mt < 2; ++mt) {
        int row0 = mt * 16 + (lane >> 4) * 4;
        #pragma unroll
        for (int r = 0; r < 4; ++r) {
            int ge = e0 + row0 + r;
            if (ge < E) {
                size_t o = (size_t)ge * D + col2;
                ef_out[o] = acc2[mt][r] + ef_in[o];
            }
        }
    }
}

extern "C" void kernel_launch(void* const* d_in, const int* in_sizes, int n_in,
                              void* d_out, int out_size, void* d_ws, size_t ws_size,
                              hipStream_t stream) {
    const float* nf_in0   = (const float*)d_in[0];
    const float* ef_in0   = (const float*)d_in[1];
    const int*   eidx     = (const int*)d_in[2];
    const float* W_lin    = (const float*)d_in[3];
    const float* W_edge   = (const float*)d_in[4];
    const float* att_src  = (const float*)d_in[5];
    const float* att_dst  = (const float*)d_in[6];
    const float* att_edge = (const float*)d_in[7];
    const float* biasc    = (const float*)d_in[8];
    const float* ln_g     = (const float*)d_in[9];
    const float* ln_b     = (const float*)d_in[10];
    const float* eW1      = (const float*)d_in[11];
    const float* eb1      = (const float*)d_in[12];
    const float* eln_g    = (const float*)d_in[13];
    const float* eln_b    = (const float*)d_in[14];
    const float* eW2      = (const float*)d_in[15];
    const float* eb2      = (const float*)d_in[16];

    int N = in_sizes[0] / D;
    int E = in_sizes[1] / D;
    const int* srcp = eidx;
    const int* dstp = eidx + E;

    float* ws      = (float*)d_ws;
    float* x       = ws;                              // N*256
    float* a_src   = x + (size_t)N * HC;              // N*4
    float* a_dst   = a_src + (size_t)N * H;           // N*4
    unsigned* amax = (unsigned*)(a_dst + (size_t)N * H); // N*4
    float* denom   = (float*)(amax + (size_t)N * H);  // N*4
    float* alpha   = denom + (size_t)N * H;           // E*4
    float* acc     = alpha + (size_t)E * H;           // N*64
    float* nf_ln   = acc + (size_t)N * D;             // N*64
    float* weff    = nf_ln + (size_t)N * D;           // 256
    u16*   W1T     = (u16*)(weff + 256);              // L*192*192 bf16
    u16*   W2T     = W1T + (size_t)NLAYERS * D3 * D3; // L*64*192 bf16

    float* out_nf = (float*)d_out;
    float* out_ef = out_nf + (size_t)N * D;

    // one-time (per launch) weight transpose+bf16 conversion
    {
        int total = NLAYERS * D3 * D3 + NLAYERS * D3 * D;
        k_cvtw<<<(total + 255) / 256, 256, 0, stream>>>(eW1, eW2, W1T, W2T);
    }

    for (int l = 0; l < NLAYERS; ++l) {
        const float* nf_cur = (l == 0) ? nf_in0 : nf_ln;
        const float* ef_cur = (l == 0) ? ef_in0 : out_ef;
        int relu_in = (l > 0) ? 1 : 0;

        // zero segment-max (enc(-inf)=0), denom, and node accumulator
        hipMemsetAsync(amax, 0, (size_t)N * H * 2 * sizeof(float), stream);
        hipMemsetAsync(acc, 0, (size_t)N * D * sizeof(float), stream);

        k_weff<<<1, 256, 0, stream>>>(W_edge + (size_t)l * D * HC, att_edge + l * H * C, weff);
        k_nodeproj<<<N, 256, 0, stream>>>(nf_cur, W_lin + (size_t)l * D * HC,
                                          att_src + l * H * C, att_dst + l * H * C,
                                          x, a_src, a_dst, N, relu_in);
        k_alpha<<<(E + 3) / 4, 256, 0, stream>>>(ef_cur, weff, srcp, dstp, a_src, a_dst,
                                                 alpha, amax, E);
        k_expdenom<<<(E * H + 255) / 256, 256, 0, stream>>>(alpha, amax, dstp, denom, E * H);
        k_aggregate<<<(E + 3) / 4, 256, 0, stream>>>(x, alpha, denom, srcp, dstp, acc, E);
        k_nodeln<<<(N + 3) / 4, 256, 0, stream>>>(acc, biasc + l * D, ln_g + l * D, ln_b + l * D,
                                                  nf_ln, (l == NLAYERS - 1) ? out_nf : nullptr, N);
        k_edgemlp_mfma<<<(E + 31) / 32, 256, 0, stream>>>(nf_ln, ef_cur, srcp, dstp,
                                                          W1T + (size_t)l * D3 * D3, eb1 + l * D3,
                                                          eln_g + l * D3, eln_b + l * D3,
                                                          W2T + (size_t)l * D3 * D, eb2 + l * D,
                                                          out_ef, E);
    }
}